// Round 15
// baseline (1782.879 us; speedup 1.0000x reference)
//
#include <hip/hip_runtime.h>

#define GAS __attribute__((address_space(1)))
#define LAS __attribute__((address_space(3)))

typedef __attribute__((ext_vector_type(8))) short bf16x8;
typedef __attribute__((ext_vector_type(4))) float f32x4;

static constexpr int Bb = 16, Ll = 2048, Hh = 512, Vv = 32000, H2 = 1024;
static constexpr int Mtot = Bb * Ll;  // 32768
static constexpr float LRc = 0.01f, EPSc = 1e-5f;

// ---- ws layout (bytes) ----
static constexpr size_t OFF_X    = 0;                                   // Mtot*Hh*4
static constexpr size_t OFF_EBF  = OFF_X   + (size_t)Mtot * Hh * 4;     // (unused)
static constexpr size_t OFF_W1BF = OFF_EBF + (size_t)Vv * Hh * 2;       // H2*Hh*2
static constexpr size_t OFF_W2BF = OFF_W1BF + (size_t)H2 * Hh * 2;      // Hh*H2*2
static constexpr size_t OFF_CTX  = OFF_W2BF + (size_t)Hh * H2 * 2;      // Bb*Hh*4
static constexpr size_t OFF_FF1  = OFF_CTX + (size_t)Bb * Hh * 4;       // chunk of ff1 (bf16)

__device__ inline unsigned short f2bf(float f) {  // RNE f32 -> bf16
  unsigned u = __float_as_uint(f);
  return (unsigned short)((u + 0x7fffu + ((u >> 16) & 1u)) >> 16);
}

// ---- minimal-instruction all-lane 64-wide sum over 8 chains (pure VALU asm) ----
__device__ __forceinline__ void bfly8(float& c0, float& c1, float& c2, float& c3,
                                      float& c4, float& c5, float& c6, float& c7) {
  float t0, t1, t2, t3, t4, t5, t6, t7;
  asm("s_nop 1\n\t"
      "v_add_f32 %0, %0, %0 quad_perm:[1,0,3,2] row_mask:0xf bank_mask:0xf\n\t"
      "v_add_f32 %1, %1, %1 quad_perm:[1,0,3,2] row_mask:0xf bank_mask:0xf\n\t"
      "v_add_f32 %2, %2, %2 quad_perm:[1,0,3,2] row_mask:0xf bank_mask:0xf\n\t"
      "v_add_f32 %3, %3, %3 quad_perm:[1,0,3,2] row_mask:0xf bank_mask:0xf\n\t"
      "v_add_f32 %4, %4, %4 quad_perm:[1,0,3,2] row_mask:0xf bank_mask:0xf\n\t"
      "v_add_f32 %5, %5, %5 quad_perm:[1,0,3,2] row_mask:0xf bank_mask:0xf\n\t"
      "v_add_f32 %6, %6, %6 quad_perm:[1,0,3,2] row_mask:0xf bank_mask:0xf\n\t"
      "v_add_f32 %7, %7, %7 quad_perm:[1,0,3,2] row_mask:0xf bank_mask:0xf\n\t"
      "v_add_f32 %0, %0, %0 quad_perm:[2,3,0,1] row_mask:0xf bank_mask:0xf\n\t"
      "v_add_f32 %1, %1, %1 quad_perm:[2,3,0,1] row_mask:0xf bank_mask:0xf\n\t"
      "v_add_f32 %2, %2, %2 quad_perm:[2,3,0,1] row_mask:0xf bank_mask:0xf\n\t"
      "v_add_f32 %3, %3, %3 quad_perm:[2,3,0,1] row_mask:0xf bank_mask:0xf\n\t"
      "v_add_f32 %4, %4, %4 quad_perm:[2,3,0,1] row_mask:0xf bank_mask:0xf\n\t"
      "v_add_f32 %5, %5, %5 quad_perm:[2,3,0,1] row_mask:0xf bank_mask:0xf\n\t"
      "v_add_f32 %6, %6, %6 quad_perm:[2,3,0,1] row_mask:0xf bank_mask:0xf\n\t"
      "v_add_f32 %7, %7, %7 quad_perm:[2,3,0,1] row_mask:0xf bank_mask:0xf\n\t"
      "v_add_f32 %0, %0, %0 row_half_mirror row_mask:0xf bank_mask:0xf\n\t"
      "v_add_f32 %1, %1, %1 row_half_mirror row_mask:0xf bank_mask:0xf\n\t"
      "v_add_f32 %2, %2, %2 row_half_mirror row_mask:0xf bank_mask:0xf\n\t"
      "v_add_f32 %3, %3, %3 row_half_mirror row_mask:0xf bank_mask:0xf\n\t"
      "v_add_f32 %4, %4, %4 row_half_mirror row_mask:0xf bank_mask:0xf\n\t"
      "v_add_f32 %5, %5, %5 row_half_mirror row_mask:0xf bank_mask:0xf\n\t"
      "v_add_f32 %6, %6, %6 row_half_mirror row_mask:0xf bank_mask:0xf\n\t"
      "v_add_f32 %7, %7, %7 row_half_mirror row_mask:0xf bank_mask:0xf\n\t"
      "v_add_f32 %0, %0, %0 row_mirror row_mask:0xf bank_mask:0xf\n\t"
      "v_add_f32 %1, %1, %1 row_mirror row_mask:0xf bank_mask:0xf\n\t"
      "v_add_f32 %2, %2, %2 row_mirror row_mask:0xf bank_mask:0xf\n\t"
      "v_add_f32 %3, %3, %3 row_mirror row_mask:0xf bank_mask:0xf\n\t"
      "v_add_f32 %4, %4, %4 row_mirror row_mask:0xf bank_mask:0xf\n\t"
      "v_add_f32 %5, %5, %5 row_mirror row_mask:0xf bank_mask:0xf\n\t"
      "v_add_f32 %6, %6, %6 row_mirror row_mask:0xf bank_mask:0xf\n\t"
      "v_add_f32 %7, %7, %7 row_mirror row_mask:0xf bank_mask:0xf\n\t"
      "v_mov_b32 %8, %0\n\t"
      "v_mov_b32 %9, %1\n\t"
      "v_mov_b32 %10, %2\n\t"
      "v_mov_b32 %11, %3\n\t"
      "v_mov_b32 %12, %4\n\t"
      "v_mov_b32 %13, %5\n\t"
      "v_mov_b32 %14, %6\n\t"
      "v_mov_b32 %15, %7\n\t"
      "v_permlane16_swap_b32 %8, %0\n\t"
      "v_permlane16_swap_b32 %9, %1\n\t"
      "v_permlane16_swap_b32 %10, %2\n\t"
      "v_permlane16_swap_b32 %11, %3\n\t"
      "v_permlane16_swap_b32 %12, %4\n\t"
      "v_permlane16_swap_b32 %13, %5\n\t"
      "v_permlane16_swap_b32 %14, %6\n\t"
      "v_permlane16_swap_b32 %15, %7\n\t"
      "v_add_f32 %0, %8, %0\n\t"
      "v_add_f32 %1, %9, %1\n\t"
      "v_add_f32 %2, %10, %2\n\t"
      "v_add_f32 %3, %11, %3\n\t"
      "v_add_f32 %4, %12, %4\n\t"
      "v_add_f32 %5, %13, %5\n\t"
      "v_add_f32 %6, %14, %6\n\t"
      "v_add_f32 %7, %15, %7\n\t"
      "v_mov_b32 %8, %0\n\t"
      "v_mov_b32 %9, %1\n\t"
      "v_mov_b32 %10, %2\n\t"
      "v_mov_b32 %11, %3\n\t"
      "v_mov_b32 %12, %4\n\t"
      "v_mov_b32 %13, %5\n\t"
      "v_mov_b32 %14, %6\n\t"
      "v_mov_b32 %15, %7\n\t"
      "v_permlane32_swap_b32 %8, %0\n\t"
      "v_permlane32_swap_b32 %9, %1\n\t"
      "v_permlane32_swap_b32 %10, %2\n\t"
      "v_permlane32_swap_b32 %11, %3\n\t"
      "v_permlane32_swap_b32 %12, %4\n\t"
      "v_permlane32_swap_b32 %13, %5\n\t"
      "v_permlane32_swap_b32 %14, %6\n\t"
      "v_permlane32_swap_b32 %15, %7\n\t"
      "v_add_f32 %0, %8, %0\n\t"
      "v_add_f32 %1, %9, %1\n\t"
      "v_add_f32 %2, %10, %2\n\t"
      "v_add_f32 %3, %11, %3\n\t"
      "v_add_f32 %4, %12, %4\n\t"
      "v_add_f32 %5, %13, %5\n\t"
      "v_add_f32 %6, %14, %6\n\t"
      "v_add_f32 %7, %15, %7"
      : "+v"(c0), "+v"(c1), "+v"(c2), "+v"(c3),
        "+v"(c4), "+v"(c5), "+v"(c6), "+v"(c7),
        "=&v"(t0), "=&v"(t1), "=&v"(t2), "=&v"(t3),
        "=&v"(t4), "=&v"(t5), "=&v"(t6), "=&v"(t7));
}

// ---------------- f32 -> bf16 conversion (w1/w2 only) ----------------
__global__ __launch_bounds__(256) void cvt_bf16_kernel(const float* __restrict__ src,
                                                       unsigned short* __restrict__ dst, int n8) {
  int stride = gridDim.x * blockDim.x;
  for (int i = blockIdx.x * blockDim.x + threadIdx.x; i < n8; i += stride) {
    const float4* p = (const float4*)(src + (size_t)i * 8);
    float4 a = p[0], b = p[1];
    uint4 o;
    o.x = f2bf(a.x) | ((unsigned)f2bf(a.y) << 16);
    o.y = f2bf(a.z) | ((unsigned)f2bf(a.w) << 16);
    o.z = f2bf(b.x) | ((unsigned)f2bf(b.y) << 16);
    o.w = f2bf(b.z) | ((unsigned)f2bf(b.w) << 16);
    *(uint4*)(dst + (size_t)i * 8) = o;
  }
}

// ---------------- bf16 GEMM, B^T layout, 128x128 tile, BK=32 (m97 + XCD swizzle) ----------------
template <int KTOT, int NT, bool GATHER, bool RELUOUT, bool AFLOAT>
__global__ __launch_bounds__(256) void gemm_bt(const unsigned short* __restrict__ Abase,
                                               const float* __restrict__ Afl,
                                               const int* __restrict__ seq, int seq_off,
                                               const unsigned short* __restrict__ Bmat,
                                               const float* __restrict__ bias,
                                               unsigned short* __restrict__ outb,
                                               float* __restrict__ outf,
                                               int out_row_off, int ldout, int mtiles) {
  __shared__ unsigned short As[128 * 32];
  __shared__ unsigned short Bs[128 * 32];
  __shared__ unsigned long long aoff[128];
  const int tid = threadIdx.x;

  const int i = blockIdx.x;
  const int s = i >> 3;
  const int m0 = ((i & 7) * (mtiles >> 3) + s / NT) * 128;
  const int n0 = (s % NT) * 128;

  if (tid < 128) {
    long long r;
    if (GATHER) r = (long long)seq[seq_off + m0 + tid] * KTOT;
    else        r = (long long)(m0 + tid) * KTOT;
    aoff[tid] = (unsigned long long)r;
  }
  __syncthreads();

  const int srow = tid >> 2;
  const int scol = (tid & 3) * 8;
  const int wave = tid >> 6;
  const int lane = tid & 63;
  const int wr = wave >> 1, wc = wave & 1;
  const int fr = lane & 15;
  const int fk = (lane >> 4) * 8;

  f32x4 acc[4][4] = {};

  for (int k0 = 0; k0 < KTOT; k0 += 32) {
#pragma unroll
    for (int i2 = 0; i2 < 2; ++i2) {
      if (AFLOAT) {
        const float* fa = Afl + aoff[i2 * 64 + srow] + k0 + scol;
        float4 a0 = *(const float4*)fa, a1 = *(const float4*)(fa + 4);
        uint4 o;
        o.x = f2bf(a0.x) | ((unsigned)f2bf(a0.y) << 16);
        o.y = f2bf(a0.z) | ((unsigned)f2bf(a0.w) << 16);
        o.z = f2bf(a1.x) | ((unsigned)f2bf(a1.y) << 16);
        o.w = f2bf(a1.z) | ((unsigned)f2bf(a1.w) << 16);
        *(uint4*)((char*)As + i2 * 4096 + (size_t)tid * 16) = o;
      } else {
        const unsigned short* ga = Abase + aoff[i2 * 64 + srow] + k0 + scol;
        __builtin_amdgcn_global_load_lds((const GAS void*)ga,
            (LAS void*)((char*)As + i2 * 4096 + wave * 1024), 16, 0, 0);
      }
      const unsigned short* gb = Bmat + (size_t)(n0 + i2 * 64 + srow) * KTOT + k0 + scol;
      __builtin_amdgcn_global_load_lds((const GAS void*)gb,
          (LAS void*)((char*)Bs + i2 * 4096 + wave * 1024), 16, 0, 0);
    }
    __syncthreads();
    bf16x8 af[4], bfr[4];
#pragma unroll
    for (int m = 0; m < 4; ++m)
      af[m] = *(const bf16x8*)&As[(wr * 64 + m * 16 + fr) * 32 + fk];
#pragma unroll
    for (int n = 0; n < 4; ++n)
      bfr[n] = *(const bf16x8*)&Bs[(wc * 64 + n * 16 + fr) * 32 + fk];
#pragma unroll
    for (int m = 0; m < 4; ++m)
#pragma unroll
      for (int n = 0; n < 4; ++n)
        acc[m][n] = __builtin_amdgcn_mfma_f32_16x16x32_bf16(af[m], bfr[n], acc[m][n], 0, 0, 0);
    __syncthreads();
  }

  float bv[4];
#pragma unroll
  for (int n = 0; n < 4; ++n) bv[n] = bias[n0 + wc * 64 + n * 16 + fr];
#pragma unroll
  for (int m = 0; m < 4; ++m) {
#pragma unroll
    for (int n = 0; n < 4; ++n) {
#pragma unroll
      for (int j = 0; j < 4; ++j) {
        int rl = wr * 64 + m * 16 + ((lane >> 4) << 2) + j;
        int col = n0 + wc * 64 + n * 16 + fr;
        float v = acc[m][n][j] + bv[n];
        size_t off = (size_t)(out_row_off + m0 + rl) * ldout + col;
        if (RELUOUT) { v = fmaxf(v, 0.f); outb[off] = f2bf(v); }
        else outf[off] = v;
      }
    }
  }
}

// ---------------- residual add + LayerNorm ----------------
__global__ __launch_bounds__(256) void ln_kernel(float* __restrict__ xbuf,
                                                 const float* __restrict__ embed,
                                                 const int* __restrict__ seq,
                                                 const float* __restrict__ lnw,
                                                 const float* __restrict__ lnb) {
  int row = blockIdx.x * 4 + (threadIdx.x >> 6);
  int lane = threadIdx.x & 63;
  int c = lane * 8;
  int s = seq[row];
  float* xr = xbuf + (size_t)row * Hh;
  const float* hr = embed + (size_t)s * Hh;
  float4 f0 = *(const float4*)(xr + c), f1 = *(const float4*)(xr + c + 4);
  float4 h0 = *(const float4*)(hr + c), h1 = *(const float4*)(hr + c + 4);
  float x[8] = {f0.x + h0.x, f0.y + h0.y, f0.z + h0.z, f0.w + h0.w,
                f1.x + h1.x, f1.y + h1.y, f1.z + h1.z, f1.w + h1.w};
  float sm = 0.f, sq = 0.f;
#pragma unroll
  for (int u = 0; u < 8; ++u) { sm += x[u]; sq += x[u] * x[u]; }
#pragma unroll
  for (int m = 1; m < 64; m <<= 1) { sm += __shfl_xor(sm, m, 64); sq += __shfl_xor(sq, m, 64); }
  float mu = sm * (1.f / 512.f);
  float var = sq * (1.f / 512.f) - mu * mu;
  float rs = rsqrtf(var + EPSc);
  float y[8];
#pragma unroll
  for (int u = 0; u < 8; ++u) y[u] = (x[u] - mu) * rs * lnw[c + u] + lnb[c + u];
  *(float4*)(xr + c) = make_float4(y[0], y[1], y[2], y[3]);
  *(float4*)(xr + c + 4) = make_float4(y[4], y[5], y[6], y[7]);
}

// ---------------- TTT scan v13: R8 body, 8 independent waves per block ----------------
// 2 blocks x 512 threads: each block = 1 CU, 8 waves over 4 SIMDs = 2 waves/SIMD.
// Waves are fully independent (one batch each, no barrier/LDS) — co-resident
// waves interleave issue into each other's dependency-stall slots.
// __launch_bounds__(512, 2): 2 waves/EU -> register cap 256/wave (fits, R9).
__global__ __launch_bounds__(512, 2) void ttt_kernel(const float* __restrict__ hidden,
                                                     const float* __restrict__ w1_0,
                                                     const float* __restrict__ b1_0,
                                                     const float* __restrict__ w2_0,
                                                     const float* __restrict__ b2_0,
                                                     float* __restrict__ ctx) {
  const int b = blockIdx.x * 8 + (threadIdx.x >> 6);
  const int l = threadIdx.x & 63;
  const int c0 = l * 8;
  const float* hb = hidden + (size_t)b * Ll * Hh;
  const float cs = -LRc * 2.0f / 512.0f;  // dL = (pred - v) * cs  (-LR folded)

  float W1[8][8];
  float W2[8][8];
  float B1[8], B2[8];
#pragma unroll
  for (int j = 0; j < 8; ++j) {
    float4 a = *(const float4*)(w1_0 + (size_t)j * Hh + c0);
    float4 d = *(const float4*)(w1_0 + (size_t)j * Hh + c0 + 4);
    W1[j][0] = a.x; W1[j][1] = a.y; W1[j][2] = a.z; W1[j][3] = a.w;
    W1[j][4] = d.x; W1[j][5] = d.y; W1[j][6] = d.z; W1[j][7] = d.w;
    B1[j] = b1_0[j];
  }
#pragma unroll
  for (int u = 0; u < 8; ++u) {
    float4 a = *(const float4*)(w2_0 + (size_t)(c0 + u) * 8);
    float4 d = *(const float4*)(w2_0 + (size_t)(c0 + u) * 8 + 4);
    W2[u][0] = a.x; W2[u][1] = a.y; W2[u][2] = a.z; W2[u][3] = a.w;
    W2[u][4] = d.x; W2[u][5] = d.y; W2[u][6] = d.z; W2[u][7] = d.w;
  }
  {
    float4 e = *(const float4*)(b2_0 + c0);
    float4 f = *(const float4*)(b2_0 + c0 + 4);
    B2[0] = e.x; B2[1] = e.y; B2[2] = e.z; B2[3] = e.w;
    B2[4] = f.x; B2[5] = f.y; B2[6] = f.z; B2[7] = f.w;
  }

  float KA[8], VA[8], KB[8], VB[8];
  {  // k_0 = row 0, v_0 = row 1
    const float* p0 = hb + c0;
    float4 a = *(const float4*)p0, d = *(const float4*)(p0 + 4);
    KA[0] = a.x; KA[1] = a.y; KA[2] = a.z; KA[3] = a.w;
    KA[4] = d.x; KA[5] = d.y; KA[6] = d.z; KA[7] = d.w;
    const float* p1 = hb + Hh + c0;
    float4 g = *(const float4*)p1, h4 = *(const float4*)(p1 + 4);
    VA[0] = g.x; VA[1] = g.y; VA[2] = g.z; VA[3] = g.w;
    VA[4] = h4.x; VA[5] = h4.y; VA[6] = h4.z; VA[7] = h4.w;
  }

#define TTT_STEP(Kc_, Vc_, Kl_, Vl_, rowb, DOLOAD)                            \
  {                                                                           \
    if (DOLOAD) {                                                             \
      const float* kr_ = hb + (size_t)(rowb)*Hh + c0;                         \
      float4 a_ = *(const float4*)kr_, b_ = *(const float4*)(kr_ + 4);        \
      float4 e_ = *(const float4*)(kr_ + Hh), f_ = *(const float4*)(kr_ + Hh + 4); \
      Kl_[0] = a_.x; Kl_[1] = a_.y; Kl_[2] = a_.z; Kl_[3] = a_.w;             \
      Kl_[4] = b_.x; Kl_[5] = b_.y; Kl_[6] = b_.z; Kl_[7] = b_.w;             \
      Vl_[0] = e_.x; Vl_[1] = e_.y; Vl_[2] = e_.z; Vl_[3] = e_.w;             \
      Vl_[4] = f_.x; Vl_[5] = f_.y; Vl_[6] = f_.z; Vl_[7] = f_.w;             \
    }                                                                         \
    float zz[8];                                                              \
    _Pragma("unroll") for (int j = 0; j < 8; ++j) {                           \
      float a0 = W1[j][0] * Kc_[0], a1 = W1[j][1] * Kc_[1];                   \
      a0 = fmaf(W1[j][2], Kc_[2], a0); a1 = fmaf(W1[j][3], Kc_[3], a1);       \
      a0 = fmaf(W1[j][4], Kc_[4], a0); a1 = fmaf(W1[j][5], Kc_[5], a1);       \
      a0 = fmaf(W1[j][6], Kc_[6], a0); a1 = fmaf(W1[j][7], Kc_[7], a1);       \
      zz[j] = a0 + a1;                                                        \
    }                                                                         \
    bfly8(zz[0], zz[1], zz[2], zz[3], zz[4], zz[5], zz[6], zz[7]);            \
    float hh[8];                                                              \
    _Pragma("unroll") for (int j = 0; j < 8; ++j) {                           \
      zz[j] += B1[j];                                                         \
      hh[j] = fmaxf(zz[j], 0.f);                                              \
    }                                                                         \
    float dLl[8];                                                             \
    _Pragma("unroll") for (int u = 0; u < 8; ++u) {                           \
      float a0 = fmaf(W2[u][0], hh[0], B2[u]), a1 = W2[u][1] * hh[1];         \
      a0 = fmaf(W2[u][2], hh[2], a0); a1 = fmaf(W2[u][3], hh[3], a1);         \
      a0 = fmaf(W2[u][4], hh[4], a0); a1 = fmaf(W2[u][5], hh[5], a1);         \
      a0 = fmaf(W2[u][6], hh[6], a0); a1 = fmaf(W2[u][7], hh[7], a1);         \
      dLl[u] = ((a0 + a1) - Vc_[u]) * cs;                                     \
    }                                                                         \
    float dh[8];                                                              \
    _Pragma("unroll") for (int d = 0; d < 8; ++d) {                           \
      float a0 = W2[0][d] * dLl[0], a1 = W2[1][d] * dLl[1];                   \
      a0 = fmaf(W2[2][d], dLl[2], a0); a1 = fmaf(W2[3][d], dLl[3], a1);       \
      a0 = fmaf(W2[4][d], dLl[4], a0); a1 = fmaf(W2[5][d], dLl[5], a1);       \
      a0 = fmaf(W2[6][d], dLl[6], a0); a1 = fmaf(W2[7][d], dLl[7], a1);       \
      dh[d] = a0 + a1;                                                        \
    }                                                                         \
    bfly8(dh[0], dh[1], dh[2], dh[3], dh[4], dh[5], dh[6], dh[7]);            \
    _Pragma("unroll") for (int u = 0; u < 8; ++u) {                           \
      _Pragma("unroll") for (int d = 0; d < 8; ++d)                           \
        W2[u][d] = fmaf(dLl[u], hh[d], W2[u][d]);                             \
      B2[u] += dLl[u];                                                        \
    }                                                                         \
    _Pragma("unroll") for (int j = 0; j < 8; ++j) {                           \
      float dzj = (zz[j] > 0.f) ? dh[j] : 0.f;                                \
      _Pragma("unroll") for (int d = 0; d < 8; ++d)                           \
        W1[j][d] = fmaf(dzj, Kc_[d], W1[j][d]);                               \
      B1[j] += dzj;                                                           \
    }                                                                         \
  }

  for (int i = 0; i < 511; ++i) {
    const int r0 = 4 * i;
    TTT_STEP(KA, VA, KB, VB, r0 + 2, true);   // step 2i, load k/v_{2i+1}
    TTT_STEP(KB, VB, KA, VA, r0 + 4, true);   // step 2i+1, load k/v_{2i+2}
  }
  TTT_STEP(KA, VA, KB, VB, 0, false);         // step 1022, no load
#undef TTT_STEP

  // ---- query: row L-1 ----
  {
    const float* pq = hb + (size_t)(Ll - 1) * Hh + c0;
    float4 a = *(const float4*)pq, d = *(const float4*)(pq + 4);
    float Q[8] = {a.x, a.y, a.z, a.w, d.x, d.y, d.z, d.w};
    float qch[8];
#pragma unroll
    for (int j = 0; j < 8; ++j) {
      float a0 = W1[j][0] * Q[0], a1 = W1[j][1] * Q[1];
      a0 = fmaf(W1[j][2], Q[2], a0); a1 = fmaf(W1[j][3], Q[3], a1);
      a0 = fmaf(W1[j][4], Q[4], a0); a1 = fmaf(W1[j][5], Q[5], a1);
      a0 = fmaf(W1[j][6], Q[6], a0); a1 = fmaf(W1[j][7], Q[7], a1);
      qch[j] = a0 + a1;
    }
    bfly8(qch[0], qch[1], qch[2], qch[3], qch[4], qch[5], qch[6], qch[7]);
    float hq[8];
#pragma unroll
    for (int j = 0; j < 8; ++j) hq[j] = fmaxf(qch[j] + B1[j], 0.f);
    float o[8];
#pragma unroll
    for (int u = 0; u < 8; ++u) {
      float a0 = fmaf(W2[u][0], hq[0], B2[u]), a1 = W2[u][1] * hq[1];
      a0 = fmaf(W2[u][2], hq[2], a0); a1 = fmaf(W2[u][3], hq[3], a1);
      a0 = fmaf(W2[u][4], hq[4], a0); a1 = fmaf(W2[u][5], hq[5], a1);
      a0 = fmaf(W2[u][6], hq[6], a0); a1 = fmaf(W2[u][7], hq[7], a1);
      o[u] = a0 + a1;
    }
    float* cp = ctx + (size_t)b * Hh + c0;
    *(float4*)cp = make_float4(o[0], o[1], o[2], o[3]);
    *(float4*)(cp + 4) = make_float4(o[4], o[5], o[6], o[7]);
  }
}

// ---------------- head: out[b,v] = ctx[b,:] @ out_w[v,:] + out_b[v] ----------------
__global__ __launch_bounds__(256) void out_kernel(const float* __restrict__ ctx,
                                                  const float* __restrict__ outw,
                                                  const float* __restrict__ outb_,
                                                  float* __restrict__ out) {
  __shared__ float cs[16 * 516];
  int tid = threadIdx.x;
#pragma unroll
  for (int r = 0; r < 32; ++r) {
    int idx = r * 256 + tid;
    cs[(idx >> 9) * 516 + (idx & 511)] = ctx[idx];
  }
  __syncthreads();
  int v = blockIdx.x * 16 + (tid >> 4);
  int b = tid & 15;
  const float4* wr = (const float4*)(outw + (size_t)v * 512);
  const float4* cr = (const float4*)(cs + b * 516);
  float acc = 0.f;
#pragma unroll 8
  for (int k = 0; k < 128; ++k) {
    float4 wv = wr[k];
    float4 cv = cr[k];
    acc += wv.x * cv.x + wv.y * cv.y + wv.z * cv.z + wv.w * cv.w;
  }
  out[(size_t)b * 32000 + v] = acc + outb_[v];
}

extern "C" void kernel_launch(void* const* d_in, const int* in_sizes, int n_in,
                              void* d_out, int out_size, void* d_ws, size_t ws_size,
                              hipStream_t stream) {
  const int*   seq    = (const int*)d_in[0];
  const float* embed  = (const float*)d_in[1];
  const float* enc_w1 = (const float*)d_in[2];
  const float* enc_b1 = (const float*)d_in[3];
  const float* enc_w2 = (const float*)d_in[4];
  const float* enc_b2 = (const float*)d_in[5];
  const float* ln_w   = (const float*)d_in[6];
  const float* ln_b   = (const float*)d_in[7];
  const float* mlp_w1 = (const float*)d_in[8];
  const float* mlp_b1 = (const float*)d_in[9];
  const float* mlp_w2 = (const float*)d_in[10];
  const float* mlp_b2 = (const float*)d_in[11];
  const float* out_w  = (const float*)d_in[12];
  const float* out_b  = (const float*)d_in[13];
  float* out = (float*)d_out;

  char* ws = (char*)d_ws;
  float*          xbuf = (float*)(ws + OFF_X);
  unsigned short* w1bf = (unsigned short*)(ws + OFF_W1BF);
  unsigned short* w2bf = (unsigned short*)(ws + OFF_W2BF);
  float*          ctx  = (float*)(ws + OFF_CTX);
  unsigned short* ff1  = (unsigned short*)(ws + OFF_FF1);

  const int cand[4] = {1, 2, 4, 8};
  int nc = 8;
  for (int ci = 0; ci < 4; ++ci) {
    if (OFF_FF1 + (size_t)(Mtot / cand[ci]) * H2 * 2 <= ws_size) { nc = cand[ci]; break; }
  }

  cvt_bf16_kernel<<<256, 256, 0, stream>>>(enc_w1, w1bf, H2 * Hh / 8);
  cvt_bf16_kernel<<<256, 256, 0, stream>>>(enc_w2, w2bf, Hh * H2 / 8);

  const int Mc = Mtot / nc;
  const int mtiles = Mc / 128;
  for (int c = 0; c < nc; ++c) {
    const int m0 = c * Mc;
    gemm_bt<512, 8, true, true, true><<<mtiles * 8, 256, 0, stream>>>(
        nullptr, embed, seq, m0, w1bf, enc_b1, ff1, nullptr, 0, H2, mtiles);
    gemm_bt<1024, 4, false, false, false><<<mtiles * 4, 256, 0, stream>>>(
        ff1, nullptr, nullptr, 0, w2bf, enc_b2, nullptr, xbuf, m0, Hh, mtiles);
  }
  ln_kernel<<<Mtot / 4, 256, 0, stream>>>(xbuf, embed, seq, ln_w, ln_b);
  ttt_kernel<<<2, 512, 0, stream>>>(xbuf, mlp_w1, mlp_b1, mlp_w2, mlp_b2, ctx);
  out_kernel<<<Vv / 16, 256, 0, stream>>>(ctx, out_w, out_b, out);
}

// Round 16
// 984.378 us; speedup vs baseline: 1.8112x; 1.8112x over previous
//
#include <hip/hip_runtime.h>

#define GAS __attribute__((address_space(1)))
#define LAS __attribute__((address_space(3)))

typedef __attribute__((ext_vector_type(8))) short bf16x8;
typedef __attribute__((ext_vector_type(4))) float f32x4;

static constexpr int Bb = 16, Ll = 2048, Hh = 512, Vv = 32000, H2 = 1024;
static constexpr int Mtot = Bb * Ll;  // 32768
static constexpr float LRc = 0.01f, EPSc = 1e-5f;

// ---- ws layout (bytes) ----
static constexpr size_t OFF_X    = 0;                                   // Mtot*Hh*4
static constexpr size_t OFF_EBF  = OFF_X   + (size_t)Mtot * Hh * 4;     // (unused)
static constexpr size_t OFF_W1BF = OFF_EBF + (size_t)Vv * Hh * 2;       // H2*Hh*2
static constexpr size_t OFF_W2BF = OFF_W1BF + (size_t)H2 * Hh * 2;      // Hh*H2*2
static constexpr size_t OFF_CTX  = OFF_W2BF + (size_t)Hh * H2 * 2;      // Bb*Hh*4
static constexpr size_t OFF_FF1  = OFF_CTX + (size_t)Bb * Hh * 4;       // chunk of ff1 (bf16)

__device__ inline unsigned short f2bf(float f) {  // RNE f32 -> bf16
  unsigned u = __float_as_uint(f);
  return (unsigned short)((u + 0x7fffu + ((u >> 16) & 1u)) >> 16);
}

// ---- minimal-instruction all-lane 64-wide sum over 8 chains (pure VALU asm) ----
__device__ __forceinline__ void bfly8(float& c0, float& c1, float& c2, float& c3,
                                      float& c4, float& c5, float& c6, float& c7) {
  float t0, t1, t2, t3, t4, t5, t6, t7;
  asm("s_nop 1\n\t"
      "v_add_f32 %0, %0, %0 quad_perm:[1,0,3,2] row_mask:0xf bank_mask:0xf\n\t"
      "v_add_f32 %1, %1, %1 quad_perm:[1,0,3,2] row_mask:0xf bank_mask:0xf\n\t"
      "v_add_f32 %2, %2, %2 quad_perm:[1,0,3,2] row_mask:0xf bank_mask:0xf\n\t"
      "v_add_f32 %3, %3, %3 quad_perm:[1,0,3,2] row_mask:0xf bank_mask:0xf\n\t"
      "v_add_f32 %4, %4, %4 quad_perm:[1,0,3,2] row_mask:0xf bank_mask:0xf\n\t"
      "v_add_f32 %5, %5, %5 quad_perm:[1,0,3,2] row_mask:0xf bank_mask:0xf\n\t"
      "v_add_f32 %6, %6, %6 quad_perm:[1,0,3,2] row_mask:0xf bank_mask:0xf\n\t"
      "v_add_f32 %7, %7, %7 quad_perm:[1,0,3,2] row_mask:0xf bank_mask:0xf\n\t"
      "v_add_f32 %0, %0, %0 quad_perm:[2,3,0,1] row_mask:0xf bank_mask:0xf\n\t"
      "v_add_f32 %1, %1, %1 quad_perm:[2,3,0,1] row_mask:0xf bank_mask:0xf\n\t"
      "v_add_f32 %2, %2, %2 quad_perm:[2,3,0,1] row_mask:0xf bank_mask:0xf\n\t"
      "v_add_f32 %3, %3, %3 quad_perm:[2,3,0,1] row_mask:0xf bank_mask:0xf\n\t"
      "v_add_f32 %4, %4, %4 quad_perm:[2,3,0,1] row_mask:0xf bank_mask:0xf\n\t"
      "v_add_f32 %5, %5, %5 quad_perm:[2,3,0,1] row_mask:0xf bank_mask:0xf\n\t"
      "v_add_f32 %6, %6, %6 quad_perm:[2,3,0,1] row_mask:0xf bank_mask:0xf\n\t"
      "v_add_f32 %7, %7, %7 quad_perm:[2,3,0,1] row_mask:0xf bank_mask:0xf\n\t"
      "v_add_f32 %0, %0, %0 row_half_mirror row_mask:0xf bank_mask:0xf\n\t"
      "v_add_f32 %1, %1, %1 row_half_mirror row_mask:0xf bank_mask:0xf\n\t"
      "v_add_f32 %2, %2, %2 row_half_mirror row_mask:0xf bank_mask:0xf\n\t"
      "v_add_f32 %3, %3, %3 row_half_mirror row_mask:0xf bank_mask:0xf\n\t"
      "v_add_f32 %4, %4, %4 row_half_mirror row_mask:0xf bank_mask:0xf\n\t"
      "v_add_f32 %5, %5, %5 row_half_mirror row_mask:0xf bank_mask:0xf\n\t"
      "v_add_f32 %6, %6, %6 row_half_mirror row_mask:0xf bank_mask:0xf\n\t"
      "v_add_f32 %7, %7, %7 row_half_mirror row_mask:0xf bank_mask:0xf\n\t"
      "v_add_f32 %0, %0, %0 row_mirror row_mask:0xf bank_mask:0xf\n\t"
      "v_add_f32 %1, %1, %1 row_mirror row_mask:0xf bank_mask:0xf\n\t"
      "v_add_f32 %2, %2, %2 row_mirror row_mask:0xf bank_mask:0xf\n\t"
      "v_add_f32 %3, %3, %3 row_mirror row_mask:0xf bank_mask:0xf\n\t"
      "v_add_f32 %4, %4, %4 row_mirror row_mask:0xf bank_mask:0xf\n\t"
      "v_add_f32 %5, %5, %5 row_mirror row_mask:0xf bank_mask:0xf\n\t"
      "v_add_f32 %6, %6, %6 row_mirror row_mask:0xf bank_mask:0xf\n\t"
      "v_add_f32 %7, %7, %7 row_mirror row_mask:0xf bank_mask:0xf\n\t"
      "v_mov_b32 %8, %0\n\t"
      "v_mov_b32 %9, %1\n\t"
      "v_mov_b32 %10, %2\n\t"
      "v_mov_b32 %11, %3\n\t"
      "v_mov_b32 %12, %4\n\t"
      "v_mov_b32 %13, %5\n\t"
      "v_mov_b32 %14, %6\n\t"
      "v_mov_b32 %15, %7\n\t"
      "v_permlane16_swap_b32 %8, %0\n\t"
      "v_permlane16_swap_b32 %9, %1\n\t"
      "v_permlane16_swap_b32 %10, %2\n\t"
      "v_permlane16_swap_b32 %11, %3\n\t"
      "v_permlane16_swap_b32 %12, %4\n\t"
      "v_permlane16_swap_b32 %13, %5\n\t"
      "v_permlane16_swap_b32 %14, %6\n\t"
      "v_permlane16_swap_b32 %15, %7\n\t"
      "v_add_f32 %0, %8, %0\n\t"
      "v_add_f32 %1, %9, %1\n\t"
      "v_add_f32 %2, %10, %2\n\t"
      "v_add_f32 %3, %11, %3\n\t"
      "v_add_f32 %4, %12, %4\n\t"
      "v_add_f32 %5, %13, %5\n\t"
      "v_add_f32 %6, %14, %6\n\t"
      "v_add_f32 %7, %15, %7\n\t"
      "v_mov_b32 %8, %0\n\t"
      "v_mov_b32 %9, %1\n\t"
      "v_mov_b32 %10, %2\n\t"
      "v_mov_b32 %11, %3\n\t"
      "v_mov_b32 %12, %4\n\t"
      "v_mov_b32 %13, %5\n\t"
      "v_mov_b32 %14, %6\n\t"
      "v_mov_b32 %15, %7\n\t"
      "v_permlane32_swap_b32 %8, %0\n\t"
      "v_permlane32_swap_b32 %9, %1\n\t"
      "v_permlane32_swap_b32 %10, %2\n\t"
      "v_permlane32_swap_b32 %11, %3\n\t"
      "v_permlane32_swap_b32 %12, %4\n\t"
      "v_permlane32_swap_b32 %13, %5\n\t"
      "v_permlane32_swap_b32 %14, %6\n\t"
      "v_permlane32_swap_b32 %15, %7\n\t"
      "v_add_f32 %0, %8, %0\n\t"
      "v_add_f32 %1, %9, %1\n\t"
      "v_add_f32 %2, %10, %2\n\t"
      "v_add_f32 %3, %11, %3\n\t"
      "v_add_f32 %4, %12, %4\n\t"
      "v_add_f32 %5, %13, %5\n\t"
      "v_add_f32 %6, %14, %6\n\t"
      "v_add_f32 %7, %15, %7"
      : "+v"(c0), "+v"(c1), "+v"(c2), "+v"(c3),
        "+v"(c4), "+v"(c5), "+v"(c6), "+v"(c7),
        "=&v"(t0), "=&v"(t1), "=&v"(t2), "=&v"(t3),
        "=&v"(t4), "=&v"(t5), "=&v"(t6), "=&v"(t7));
}

// ---------------- f32 -> bf16 conversion (w1/w2 only) ----------------
__global__ __launch_bounds__(256) void cvt_bf16_kernel(const float* __restrict__ src,
                                                       unsigned short* __restrict__ dst, int n8) {
  int stride = gridDim.x * blockDim.x;
  for (int i = blockIdx.x * blockDim.x + threadIdx.x; i < n8; i += stride) {
    const float4* p = (const float4*)(src + (size_t)i * 8);
    float4 a = p[0], b = p[1];
    uint4 o;
    o.x = f2bf(a.x) | ((unsigned)f2bf(a.y) << 16);
    o.y = f2bf(a.z) | ((unsigned)f2bf(a.w) << 16);
    o.z = f2bf(b.x) | ((unsigned)f2bf(b.y) << 16);
    o.w = f2bf(b.z) | ((unsigned)f2bf(b.w) << 16);
    *(uint4*)(dst + (size_t)i * 8) = o;
  }
}

// ---------------- bf16 GEMM, B^T layout, 128x128 tile, BK=32 (m97 + XCD swizzle) ----------------
template <int KTOT, int NT, bool GATHER, bool RELUOUT, bool AFLOAT>
__global__ __launch_bounds__(256) void gemm_bt(const unsigned short* __restrict__ Abase,
                                               const float* __restrict__ Afl,
                                               const int* __restrict__ seq, int seq_off,
                                               const unsigned short* __restrict__ Bmat,
                                               const float* __restrict__ bias,
                                               unsigned short* __restrict__ outb,
                                               float* __restrict__ outf,
                                               int out_row_off, int ldout, int mtiles) {
  __shared__ unsigned short As[128 * 32];
  __shared__ unsigned short Bs[128 * 32];
  __shared__ unsigned long long aoff[128];
  const int tid = threadIdx.x;

  const int i = blockIdx.x;
  const int s = i >> 3;
  const int m0 = ((i & 7) * (mtiles >> 3) + s / NT) * 128;
  const int n0 = (s % NT) * 128;

  if (tid < 128) {
    long long r;
    if (GATHER) r = (long long)seq[seq_off + m0 + tid] * KTOT;
    else        r = (long long)(m0 + tid) * KTOT;
    aoff[tid] = (unsigned long long)r;
  }
  __syncthreads();

  const int srow = tid >> 2;
  const int scol = (tid & 3) * 8;
  const int wave = tid >> 6;
  const int lane = tid & 63;
  const int wr = wave >> 1, wc = wave & 1;
  const int fr = lane & 15;
  const int fk = (lane >> 4) * 8;

  f32x4 acc[4][4] = {};

  for (int k0 = 0; k0 < KTOT; k0 += 32) {
#pragma unroll
    for (int i2 = 0; i2 < 2; ++i2) {
      if (AFLOAT) {
        const float* fa = Afl + aoff[i2 * 64 + srow] + k0 + scol;
        float4 a0 = *(const float4*)fa, a1 = *(const float4*)(fa + 4);
        uint4 o;
        o.x = f2bf(a0.x) | ((unsigned)f2bf(a0.y) << 16);
        o.y = f2bf(a0.z) | ((unsigned)f2bf(a0.w) << 16);
        o.z = f2bf(a1.x) | ((unsigned)f2bf(a1.y) << 16);
        o.w = f2bf(a1.z) | ((unsigned)f2bf(a1.w) << 16);
        *(uint4*)((char*)As + i2 * 4096 + (size_t)tid * 16) = o;
      } else {
        const unsigned short* ga = Abase + aoff[i2 * 64 + srow] + k0 + scol;
        __builtin_amdgcn_global_load_lds((const GAS void*)ga,
            (LAS void*)((char*)As + i2 * 4096 + wave * 1024), 16, 0, 0);
      }
      const unsigned short* gb = Bmat + (size_t)(n0 + i2 * 64 + srow) * KTOT + k0 + scol;
      __builtin_amdgcn_global_load_lds((const GAS void*)gb,
          (LAS void*)((char*)Bs + i2 * 4096 + wave * 1024), 16, 0, 0);
    }
    __syncthreads();
    bf16x8 af[4], bfr[4];
#pragma unroll
    for (int m = 0; m < 4; ++m)
      af[m] = *(const bf16x8*)&As[(wr * 64 + m * 16 + fr) * 32 + fk];
#pragma unroll
    for (int n = 0; n < 4; ++n)
      bfr[n] = *(const bf16x8*)&Bs[(wc * 64 + n * 16 + fr) * 32 + fk];
#pragma unroll
    for (int m = 0; m < 4; ++m)
#pragma unroll
      for (int n = 0; n < 4; ++n)
        acc[m][n] = __builtin_amdgcn_mfma_f32_16x16x32_bf16(af[m], bfr[n], acc[m][n], 0, 0, 0);
    __syncthreads();
  }

  float bv[4];
#pragma unroll
  for (int n = 0; n < 4; ++n) bv[n] = bias[n0 + wc * 64 + n * 16 + fr];
#pragma unroll
  for (int m = 0; m < 4; ++m) {
#pragma unroll
    for (int n = 0; n < 4; ++n) {
#pragma unroll
      for (int j = 0; j < 4; ++j) {
        int rl = wr * 64 + m * 16 + ((lane >> 4) << 2) + j;
        int col = n0 + wc * 64 + n * 16 + fr;
        float v = acc[m][n][j] + bv[n];
        size_t off = (size_t)(out_row_off + m0 + rl) * ldout + col;
        if (RELUOUT) { v = fmaxf(v, 0.f); outb[off] = f2bf(v); }
        else outf[off] = v;
      }
    }
  }
}

// ---------------- residual add + LayerNorm ----------------
__global__ __launch_bounds__(256) void ln_kernel(float* __restrict__ xbuf,
                                                 const float* __restrict__ embed,
                                                 const int* __restrict__ seq,
                                                 const float* __restrict__ lnw,
                                                 const float* __restrict__ lnb) {
  int row = blockIdx.x * 4 + (threadIdx.x >> 6);
  int lane = threadIdx.x & 63;
  int c = lane * 8;
  int s = seq[row];
  float* xr = xbuf + (size_t)row * Hh;
  const float* hr = embed + (size_t)s * Hh;
  float4 f0 = *(const float4*)(xr + c), f1 = *(const float4*)(xr + c + 4);
  float4 h0 = *(const float4*)(hr + c), h1 = *(const float4*)(hr + c + 4);
  float x[8] = {f0.x + h0.x, f0.y + h0.y, f0.z + h0.z, f0.w + h0.w,
                f1.x + h1.x, f1.y + h1.y, f1.z + h1.z, f1.w + h1.w};
  float sm = 0.f, sq = 0.f;
#pragma unroll
  for (int u = 0; u < 8; ++u) { sm += x[u]; sq += x[u] * x[u]; }
#pragma unroll
  for (int m = 1; m < 64; m <<= 1) { sm += __shfl_xor(sm, m, 64); sq += __shfl_xor(sq, m, 64); }
  float mu = sm * (1.f / 512.f);
  float var = sq * (1.f / 512.f) - mu * mu;
  float rs = rsqrtf(var + EPSc);
  float y[8];
#pragma unroll
  for (int u = 0; u < 8; ++u) y[u] = (x[u] - mu) * rs * lnw[c + u] + lnb[c + u];
  *(float4*)(xr + c) = make_float4(y[0], y[1], y[2], y[3]);
  *(float4*)(xr + c + 4) = make_float4(y[4], y[5], y[6], y[7]);
}

// ---------------- TTT scan v10 (R8 exact): scalar math, asm butterflies, ping-pong ----------------
__global__ __launch_bounds__(64, 1) void ttt_kernel(const float* __restrict__ hidden,
                                                    const float* __restrict__ w1_0,
                                                    const float* __restrict__ b1_0,
                                                    const float* __restrict__ w2_0,
                                                    const float* __restrict__ b2_0,
                                                    float* __restrict__ ctx) {
  const int b = blockIdx.x;
  const int l = threadIdx.x;
  const int c0 = l * 8;
  const float* hb = hidden + (size_t)b * Ll * Hh;
  const float cs = -LRc * 2.0f / 512.0f;  // dL = (pred - v) * cs  (-LR folded)

  float W1[8][8];
  float W2[8][8];
  float B1[8], B2[8];
#pragma unroll
  for (int j = 0; j < 8; ++j) {
    float4 a = *(const float4*)(w1_0 + (size_t)j * Hh + c0);
    float4 d = *(const float4*)(w1_0 + (size_t)j * Hh + c0 + 4);
    W1[j][0] = a.x; W1[j][1] = a.y; W1[j][2] = a.z; W1[j][3] = a.w;
    W1[j][4] = d.x; W1[j][5] = d.y; W1[j][6] = d.z; W1[j][7] = d.w;
    B1[j] = b1_0[j];
  }
#pragma unroll
  for (int u = 0; u < 8; ++u) {
    float4 a = *(const float4*)(w2_0 + (size_t)(c0 + u) * 8);
    float4 d = *(const float4*)(w2_0 + (size_t)(c0 + u) * 8 + 4);
    W2[u][0] = a.x; W2[u][1] = a.y; W2[u][2] = a.z; W2[u][3] = a.w;
    W2[u][4] = d.x; W2[u][5] = d.y; W2[u][6] = d.z; W2[u][7] = d.w;
  }
  {
    float4 e = *(const float4*)(b2_0 + c0);
    float4 f = *(const float4*)(b2_0 + c0 + 4);
    B2[0] = e.x; B2[1] = e.y; B2[2] = e.z; B2[3] = e.w;
    B2[4] = f.x; B2[5] = f.y; B2[6] = f.z; B2[7] = f.w;
  }

  float KA[8], VA[8], KB[8], VB[8];
  {  // k_0 = row 0, v_0 = row 1
    const float* p0 = hb + c0;
    float4 a = *(const float4*)p0, d = *(const float4*)(p0 + 4);
    KA[0] = a.x; KA[1] = a.y; KA[2] = a.z; KA[3] = a.w;
    KA[4] = d.x; KA[5] = d.y; KA[6] = d.z; KA[7] = d.w;
    const float* p1 = hb + Hh + c0;
    float4 g = *(const float4*)p1, h4 = *(const float4*)(p1 + 4);
    VA[0] = g.x; VA[1] = g.y; VA[2] = g.z; VA[3] = g.w;
    VA[4] = h4.x; VA[5] = h4.y; VA[6] = h4.z; VA[7] = h4.w;
  }

#define TTT_STEP(Kc_, Vc_, Kl_, Vl_, rowb, DOLOAD)                            \
  {                                                                           \
    if (DOLOAD) {                                                             \
      const float* kr_ = hb + (size_t)(rowb)*Hh + c0;                         \
      float4 a_ = *(const float4*)kr_, b_ = *(const float4*)(kr_ + 4);        \
      float4 e_ = *(const float4*)(kr_ + Hh), f_ = *(const float4*)(kr_ + Hh + 4); \
      Kl_[0] = a_.x; Kl_[1] = a_.y; Kl_[2] = a_.z; Kl_[3] = a_.w;             \
      Kl_[4] = b_.x; Kl_[5] = b_.y; Kl_[6] = b_.z; Kl_[7] = b_.w;             \
      Vl_[0] = e_.x; Vl_[1] = e_.y; Vl_[2] = e_.z; Vl_[3] = e_.w;             \
      Vl_[4] = f_.x; Vl_[5] = f_.y; Vl_[6] = f_.z; Vl_[7] = f_.w;             \
    }                                                                         \
    float zz[8];                                                              \
    _Pragma("unroll") for (int j = 0; j < 8; ++j) {                           \
      float a0 = W1[j][0] * Kc_[0], a1 = W1[j][1] * Kc_[1];                   \
      a0 = fmaf(W1[j][2], Kc_[2], a0); a1 = fmaf(W1[j][3], Kc_[3], a1);       \
      a0 = fmaf(W1[j][4], Kc_[4], a0); a1 = fmaf(W1[j][5], Kc_[5], a1);       \
      a0 = fmaf(W1[j][6], Kc_[6], a0); a1 = fmaf(W1[j][7], Kc_[7], a1);       \
      zz[j] = a0 + a1;                                                        \
    }                                                                         \
    bfly8(zz[0], zz[1], zz[2], zz[3], zz[4], zz[5], zz[6], zz[7]);            \
    float hh[8];                                                              \
    _Pragma("unroll") for (int j = 0; j < 8; ++j) {                           \
      zz[j] += B1[j];                                                         \
      hh[j] = fmaxf(zz[j], 0.f);                                              \
    }                                                                         \
    float dLl[8];                                                             \
    _Pragma("unroll") for (int u = 0; u < 8; ++u) {                           \
      float a0 = fmaf(W2[u][0], hh[0], B2[u]), a1 = W2[u][1] * hh[1];         \
      a0 = fmaf(W2[u][2], hh[2], a0); a1 = fmaf(W2[u][3], hh[3], a1);         \
      a0 = fmaf(W2[u][4], hh[4], a0); a1 = fmaf(W2[u][5], hh[5], a1);         \
      a0 = fmaf(W2[u][6], hh[6], a0); a1 = fmaf(W2[u][7], hh[7], a1);         \
      dLl[u] = ((a0 + a1) - Vc_[u]) * cs;                                     \
    }                                                                         \
    float dh[8];                                                              \
    _Pragma("unroll") for (int d = 0; d < 8; ++d) {                           \
      float a0 = W2[0][d] * dLl[0], a1 = W2[1][d] * dLl[1];                   \
      a0 = fmaf(W2[2][d], dLl[2], a0); a1 = fmaf(W2[3][d], dLl[3], a1);       \
      a0 = fmaf(W2[4][d], dLl[4], a0); a1 = fmaf(W2[5][d], dLl[5], a1);       \
      a0 = fmaf(W2[6][d], dLl[6], a0); a1 = fmaf(W2[7][d], dLl[7], a1);       \
      dh[d] = a0 + a1;                                                        \
    }                                                                         \
    bfly8(dh[0], dh[1], dh[2], dh[3], dh[4], dh[5], dh[6], dh[7]);            \
    _Pragma("unroll") for (int u = 0; u < 8; ++u) {                           \
      _Pragma("unroll") for (int d = 0; d < 8; ++d)                           \
        W2[u][d] = fmaf(dLl[u], hh[d], W2[u][d]);                             \
      B2[u] += dLl[u];                                                        \
    }                                                                         \
    _Pragma("unroll") for (int j = 0; j < 8; ++j) {                           \
      float dzj = (zz[j] > 0.f) ? dh[j] : 0.f;                                \
      _Pragma("unroll") for (int d = 0; d < 8; ++d)                           \
        W1[j][d] = fmaf(dzj, Kc_[d], W1[j][d]);                               \
      B1[j] += dzj;                                                           \
    }                                                                         \
  }

  for (int i = 0; i < 511; ++i) {
    const int r0 = 4 * i;
    TTT_STEP(KA, VA, KB, VB, r0 + 2, true);   // step 2i, load k/v_{2i+1}
    TTT_STEP(KB, VB, KA, VA, r0 + 4, true);   // step 2i+1, load k/v_{2i+2}
  }
  TTT_STEP(KA, VA, KB, VB, 0, false);         // step 1022, no load
#undef TTT_STEP

  // ---- query: row L-1 ----
  {
    const float* pq = hb + (size_t)(Ll - 1) * Hh + c0;
    float4 a = *(const float4*)pq, d = *(const float4*)(pq + 4);
    float Q[8] = {a.x, a.y, a.z, a.w, d.x, d.y, d.z, d.w};
    float qch[8];
#pragma unroll
    for (int j = 0; j < 8; ++j) {
      float a0 = W1[j][0] * Q[0], a1 = W1[j][1] * Q[1];
      a0 = fmaf(W1[j][2], Q[2], a0); a1 = fmaf(W1[j][3], Q[3], a1);
      a0 = fmaf(W1[j][4], Q[4], a0); a1 = fmaf(W1[j][5], Q[5], a1);
      a0 = fmaf(W1[j][6], Q[6], a0); a1 = fmaf(W1[j][7], Q[7], a1);
      qch[j] = a0 + a1;
    }
    bfly8(qch[0], qch[1], qch[2], qch[3], qch[4], qch[5], qch[6], qch[7]);
    float hq[8];
#pragma unroll
    for (int j = 0; j < 8; ++j) hq[j] = fmaxf(qch[j] + B1[j], 0.f);
    float o[8];
#pragma unroll
    for (int u = 0; u < 8; ++u) {
      float a0 = fmaf(W2[u][0], hq[0], B2[u]), a1 = W2[u][1] * hq[1];
      a0 = fmaf(W2[u][2], hq[2], a0); a1 = fmaf(W2[u][3], hq[3], a1);
      a0 = fmaf(W2[u][4], hq[4], a0); a1 = fmaf(W2[u][5], hq[5], a1);
      a0 = fmaf(W2[u][6], hq[6], a0); a1 = fmaf(W2[u][7], hq[7], a1);
      o[u] = a0 + a1;
    }
    float* cp = ctx + (size_t)b * Hh + c0;
    *(float4*)cp = make_float4(o[0], o[1], o[2], o[3]);
    *(float4*)(cp + 4) = make_float4(o[4], o[5], o[6], o[7]);
  }
}

// ---------------- head: out[b,v] = ctx[b,:] @ out_w[v,:] + out_b[v] ----------------
__global__ __launch_bounds__(256) void out_kernel(const float* __restrict__ ctx,
                                                  const float* __restrict__ outw,
                                                  const float* __restrict__ outb_,
                                                  float* __restrict__ out) {
  __shared__ float cs[16 * 516];
  int tid = threadIdx.x;
#pragma unroll
  for (int r = 0; r < 32; ++r) {
    int idx = r * 256 + tid;
    cs[(idx >> 9) * 516 + (idx & 511)] = ctx[idx];
  }
  __syncthreads();
  int v = blockIdx.x * 16 + (tid >> 4);
  int b = tid & 15;
  const float4* wr = (const float4*)(outw + (size_t)v * 512);
  const float4* cr = (const float4*)(cs + b * 516);
  float acc = 0.f;
#pragma unroll 8
  for (int k = 0; k < 128; ++k) {
    float4 wv = wr[k];
    float4 cv = cr[k];
    acc += wv.x * cv.x + wv.y * cv.y + wv.z * cv.z + wv.w * cv.w;
  }
  out[(size_t)b * 32000 + v] = acc + outb_[v];
}

extern "C" void kernel_launch(void* const* d_in, const int* in_sizes, int n_in,
                              void* d_out, int out_size, void* d_ws, size_t ws_size,
                              hipStream_t stream) {
  const int*   seq    = (const int*)d_in[0];
  const float* embed  = (const float*)d_in[1];
  const float* enc_w1 = (const float*)d_in[2];
  const float* enc_b1 = (const float*)d_in[3];
  const float* enc_w2 = (const float*)d_in[4];
  const float* enc_b2 = (const float*)d_in[5];
  const float* ln_w   = (const float*)d_in[6];
  const float* ln_b   = (const float*)d_in[7];
  const float* mlp_w1 = (const float*)d_in[8];
  const float* mlp_b1 = (const float*)d_in[9];
  const float* mlp_w2 = (const float*)d_in[10];
  const float* mlp_b2 = (const float*)d_in[11];
  const float* out_w  = (const float*)d_in[12];
  const float* out_b  = (const float*)d_in[13];
  float* out = (float*)d_out;

  char* ws = (char*)d_ws;
  float*          xbuf = (float*)(ws + OFF_X);
  unsigned short* w1bf = (unsigned short*)(ws + OFF_W1BF);
  unsigned short* w2bf = (unsigned short*)(ws + OFF_W2BF);
  float*          ctx  = (float*)(ws + OFF_CTX);
  unsigned short* ff1  = (unsigned short*)(ws + OFF_FF1);

  const int cand[4] = {1, 2, 4, 8};
  int nc = 8;
  for (int ci = 0; ci < 4; ++ci) {
    if (OFF_FF1 + (size_t)(Mtot / cand[ci]) * H2 * 2 <= ws_size) { nc = cand[ci]; break; }
  }

  cvt_bf16_kernel<<<256, 256, 0, stream>>>(enc_w1, w1bf, H2 * Hh / 8);
  cvt_bf16_kernel<<<256, 256, 0, stream>>>(enc_w2, w2bf, Hh * H2 / 8);

  const int Mc = Mtot / nc;
  const int mtiles = Mc / 128;
  for (int c = 0; c < nc; ++c) {
    const int m0 = c * Mc;
    gemm_bt<512, 8, true, true, true><<<mtiles * 8, 256, 0, stream>>>(
        nullptr, embed, seq, m0, w1bf, enc_b1, ff1, nullptr, 0, H2, mtiles);
    gemm_bt<1024, 4, false, false, false><<<mtiles * 4, 256, 0, stream>>>(
        ff1, nullptr, nullptr, 0, w2bf, enc_b2, nullptr, xbuf, m0, Hh, mtiles);
  }
  ln_kernel<<<Mtot / 4, 256, 0, stream>>>(xbuf, embed, seq, ln_w, ln_b);
  ttt_kernel<<<Bb, 64, 0, stream>>>(xbuf, mlp_w1, mlp_b1, mlp_w2, mlp_b2, ctx);
  out_kernel<<<Vv / 16, 256, 0, stream>>>(ctx, out_w, out_b, out);
}